// Round 2
// baseline (136.622 us; speedup 1.0000x reference)
//
#include <hip/hip_runtime.h>

// DiscoveryNet: out[b] = 0.5 * sum over ordered off-diagonal pairs of
//   MLP([r, 1/r, 1/r^2]), r = max(dist, 0.05).  v(r) symmetric in (i,j)
//   => sum over unordered pairs of a 1-D function v(r).
// Single fused dispatch:
//   producer: block k tabulates v at entries 16k..16k+15 (block 0 also
//     entry 8192) via h1-in-LDS GEMV; publishes with agent release fence +
//     double-magic flags (poison-proof, stale-proof: data is deterministic).
//   consumer: spin on all 512 flags, acquire fence, stage tab (32.8KB) +
//     pos (float4) in LDS, interp its pair chunk, publish block partial;
//   8 reducer blocks (c==0) spin on their batch's 64 partials -> out[b].
// No atomics on out, no out-zeroing needed.

#define NPTS   512
#define HDIM   128
#define NBATCH 8
#define TN     8192               // intervals; table has TN+1 entries
#define R0     0.05f
#define RMAX   20.05f
#define DELTA  ((RMAX - R0) / (float)TN)
#define EPB    16                 // table entries produced per block
#define NBLK   512
#define NCHUNK 64
#define CHUNK  2044               // 130816 / 64 exact

#define MAG_TA 0x5EEDBA5E
#define MAG_TB 0x7C3A91F4
#define MAG_PA 0x2F9D4E63
#define MAG_PB 0xB4E19A27

__device__ __forceinline__ float silu_f(float x) {
    float e = __expf(-x);
    return x * __builtin_amdgcn_rcpf(1.0f + e);
}

__global__ __launch_bounds__(256, 2) void fused_kernel(
    const float* __restrict__ pos,
    const float* __restrict__ W1, const float* __restrict__ b1,
    const float* __restrict__ W2, const float* __restrict__ b2,
    const float* __restrict__ W3, const float* __restrict__ b3,
    float* __restrict__ ws, float* __restrict__ out)
{
    __shared__ __align__(16) float h1L[EPB][HDIM];   // 8 KB
    __shared__ float4 tabL4[2050];                   // 32.8 KB
    __shared__ float4 posL[NPTS];                    // 8 KB
    __shared__ float  wsum[4];
    float* tabL = (float*)tabL4;

    // workspace layout (dword offsets): tab[0..8192] @0, part[512] @8704,
    // tfA @9728, tfB @10240, pfA @10752, pfB @11264
    float* tab  = ws;
    float* part = ws + 8704;
    int*   tfA  = (int*)ws + 9728;
    int*   tfB  = (int*)ws + 10240;
    int*   pfA  = (int*)ws + 10752;
    int*   pfB  = (int*)ws + 11264;

    const int t    = threadIdx.x;
    const int blk  = blockIdx.x;
    const int b    = blk >> 6;               // batch
    const int c    = blk & (NCHUNK - 1);     // chunk
    const int lane = t & 63;
    const int wave = t >> 6;

    // ---- stage pos early: global latency hides under producer compute ----
    const float* __restrict__ pb = pos + b * (NPTS * 3);
    for (int i = t; i < NPTS; i += 256)
        posL[i] = make_float4(pb[3 * i], pb[3 * i + 1], pb[3 * i + 2], 0.0f);

    // ---- producer phase A: h1 = silu(feats@W1+b1) for 16 entries ----
    const int ebase = blk * EPB;
    {
        const int h = t & 127;
        const float w1a = W1[h], w1b = W1[HDIM + h], w1c = W1[2 * HDIM + h];
        const float bb1 = b1[h];
        #pragma unroll
        for (int v = 0; v < 8; ++v) {
            const int   eloc = (t >> 7) + 2 * v;          // covers 0..15
            const float r    = R0 + (float)(ebase + eloc) * DELTA;
            const float rinv = __builtin_amdgcn_rcpf(r);
            const float pre  = fmaf(r, w1a,
                               fmaf(rinv, w1b,
                               fmaf(rinv * rinv, w1c, bb1)));
            h1L[eloc][h] = silu_f(pre);
        }
    }
    __syncthreads();

    // ---- producer phase B: GEMV vs W2, silu, dot W3 -> tab slice ----
    const float2* __restrict__ W2v = (const float2*)W2;
    const float2 b2v  = ((const float2*)b2)[lane];
    const float2 w3v  = ((const float2*)W3)[lane];
    const float bias3 = b3[0];
    {
        const int ew = wave * 4;                 // wave owns 4 entries
        float2 acc[4];
        #pragma unroll
        for (int g = 0; g < 4; ++g) acc[g] = b2v;

        #pragma unroll 4
        for (int hh = 0; hh < HDIM; hh += 4) {
            const float2 w2_0 = W2v[(hh + 0) * 64 + lane];
            const float2 w2_1 = W2v[(hh + 1) * 64 + lane];
            const float2 w2_2 = W2v[(hh + 2) * 64 + lane];
            const float2 w2_3 = W2v[(hh + 3) * 64 + lane];
            #pragma unroll
            for (int g = 0; g < 4; ++g) {
                const float4 hv = *(const float4*)&h1L[ew + g][hh];  // broadcast
                acc[g].x = fmaf(hv.x, w2_0.x, acc[g].x);
                acc[g].y = fmaf(hv.x, w2_0.y, acc[g].y);
                acc[g].x = fmaf(hv.y, w2_1.x, acc[g].x);
                acc[g].y = fmaf(hv.y, w2_1.y, acc[g].y);
                acc[g].x = fmaf(hv.z, w2_2.x, acc[g].x);
                acc[g].y = fmaf(hv.z, w2_2.y, acc[g].y);
                acc[g].x = fmaf(hv.w, w2_3.x, acc[g].x);
                acc[g].y = fmaf(hv.w, w2_3.y, acc[g].y);
            }
        }
        #pragma unroll
        for (int g = 0; g < 4; ++g) {
            float s = silu_f(acc[g].x) * w3v.x + silu_f(acc[g].y) * w3v.y;
            #pragma unroll
            for (int o = 32; o; o >>= 1) s += __shfl_xor(s, o, 64);
            if (lane == 0) tab[ebase + ew + g] = s + bias3;
        }
    }

    // ---- block 0 additionally produces entry TN (r = RMAX) ----
    if (blk == 0) {
        __syncthreads();                       // main GEMV done with h1L
        if (t < HDIM) {
            const float r    = RMAX;
            const float rinv = __builtin_amdgcn_rcpf(r);
            const float pre  = fmaf(r, W1[t],
                               fmaf(rinv, W1[HDIM + t],
                               fmaf(rinv * rinv, W1[2 * HDIM + t], b1[t])));
            h1L[0][t] = silu_f(pre);
        }
        __syncthreads();
        if (wave == 0) {
            float2 a = b2v;
            #pragma unroll 4
            for (int h = 0; h < HDIM; ++h) {
                const float hv = h1L[0][h];
                const float2 w2 = W2v[h * 64 + lane];
                a.x = fmaf(hv, w2.x, a.x);
                a.y = fmaf(hv, w2.y, a.y);
            }
            float s = silu_f(a.x) * w3v.x + silu_f(a.y) * w3v.y;
            #pragma unroll
            for (int o = 32; o; o >>= 1) s += __shfl_xor(s, o, 64);
            if (lane == 0) tab[TN] = s + bias3;
        }
    }

    // ---- publish slice: release fence + double-magic flags ----
    __syncthreads();
    if (t == 0) {
        __threadfence();   // agent-scope release (L2 writeback on gfx950)
        __hip_atomic_store(&tfA[blk], (int)(MAG_TA ^ blk), __ATOMIC_RELAXED, __HIP_MEMORY_SCOPE_AGENT);
        __hip_atomic_store(&tfB[blk], (int)(MAG_TB ^ blk), __ATOMIC_RELAXED, __HIP_MEMORY_SCOPE_AGENT);
    }

    // ---- consumer: wait for all 512 slices (2 flags per thread) ----
    for (int f = t; f < NBLK; f += 256) {
        const int ea = (int)(MAG_TA ^ f), eb = (int)(MAG_TB ^ f);
        while (__hip_atomic_load(&tfA[f], __ATOMIC_RELAXED, __HIP_MEMORY_SCOPE_AGENT) != ea ||
               __hip_atomic_load(&tfB[f], __ATOMIC_RELAXED, __HIP_MEMORY_SCOPE_AGENT) != eb)
            __builtin_amdgcn_s_sleep(4);
    }
    __threadfence();       // acquire side: invalidate, see producers' data
    __syncthreads();

    // ---- stage tab into LDS (2049 float4 covers tab[0..8192]+pad) ----
    const float4* __restrict__ tabG = (const float4*)tab;
    for (int i = t; i < 2049; i += 256) tabL4[i] = tabG[i];
    __syncthreads();

    // ---- pair loop: unordered pairs, each once ----
    //   tt < 130560: d=(tt>>9)+1 in [1,255], i=tt&511, j=(i+d)&511
    //   else:        antipodal (i, i+256), i = tt-130560 in [0,256)
    const float invD = (float)TN / (RMAX - R0);
    float acc = 0.0f;
    const int tend = (c + 1) * CHUNK;
    for (int tt = c * CHUNK + t; tt < tend; tt += 256) {
        int i, j;
        if (tt < 130560) {
            const int d = (tt >> 9) + 1;
            i = tt & 511;
            j = (i + d) & 511;
        } else {
            i = tt - 130560;
            j = i + 256;
        }
        const float4 pi = posL[i];
        const float4 pj = posL[j];
        const float dx = pi.x - pj.x;
        const float dy = pi.y - pj.y;
        const float dz = pi.z - pj.z;
        const float r2 = fmaf(dx, dx, fmaf(dy, dy, dz * dz));
        const float r  = __builtin_amdgcn_sqrtf(r2);
        float x = (r - R0) * invD;
        x = fminf(fmaxf(x, 0.0f), (float)TN - 0.0005f);
        const int   idx = (int)x;
        const float fr  = x - (float)idx;
        const float t0v = tabL[idx];
        const float t1v = tabL[idx + 1];
        acc = fmaf(fr, t1v - t0v, acc + t0v);
    }

    #pragma unroll
    for (int o = 32; o; o >>= 1) acc += __shfl_xor(acc, o, 64);
    if (lane == 0) wsum[wave] = acc;
    __syncthreads();

    // ---- publish block partial ----
    if (t == 0) {
        part[blk] = wsum[0] + wsum[1] + wsum[2] + wsum[3];
        __threadfence();
        __hip_atomic_store(&pfA[blk], (int)(MAG_PA ^ blk), __ATOMIC_RELAXED, __HIP_MEMORY_SCOPE_AGENT);
        __hip_atomic_store(&pfB[blk], (int)(MAG_PB ^ blk), __ATOMIC_RELAXED, __HIP_MEMORY_SCOPE_AGENT);
    }

    // ---- reducer (one block per batch): sum 64 partials -> out[b] ----
    if (c == 0 && t < 64) {
        const int f  = blk + t;                // blk = b*64
        const int ea = (int)(MAG_PA ^ f), eb = (int)(MAG_PB ^ f);
        while (__hip_atomic_load(&pfA[f], __ATOMIC_RELAXED, __HIP_MEMORY_SCOPE_AGENT) != ea ||
               __hip_atomic_load(&pfB[f], __ATOMIC_RELAXED, __HIP_MEMORY_SCOPE_AGENT) != eb)
            __builtin_amdgcn_s_sleep(2);
        __threadfence();
        float v = part[f];
        #pragma unroll
        for (int o = 32; o; o >>= 1) v += __shfl_xor(v, o, 64);
        if (t == 0) out[b] = v;
    }
}

extern "C" void kernel_launch(void* const* d_in, const int* in_sizes, int n_in,
                              void* d_out, int out_size, void* d_ws, size_t ws_size,
                              hipStream_t stream) {
    const float* pos = (const float*)d_in[0];
    const float* W1  = (const float*)d_in[1];
    const float* b1  = (const float*)d_in[2];
    const float* W2  = (const float*)d_in[3];
    const float* b2  = (const float*)d_in[4];
    const float* W3  = (const float*)d_in[5];
    const float* b3  = (const float*)d_in[6];
    float*       out = (float*)d_out;

    // Single fused dispatch: 512 blocks, guaranteed co-resident
    // (LDS 49.2 KB -> 3 blocks/CU; __launch_bounds__(256,2) -> >=2/CU -> 512 fit).
    fused_kernel<<<dim3(NBLK), dim3(256), 0, stream>>>(
        pos, W1, b1, W2, b2, W3, b3, (float*)d_ws, out);
}

// Round 3
// 88.461 us; speedup vs baseline: 1.5444x; 1.5444x over previous
//
#include <hip/hip_runtime.h>

// DiscoveryNet: out[b] = 0.5 * sum over ordered off-diagonal pairs of
//   MLP([r, 1/r, 1/r^2]), r = max(dist, 0.05).  v depends only on r and is
//   symmetric => sum over unordered pairs of a 1-D function v(r).
// Plan: tabulate v(r) (TN+1 points); pairs do sqrt + linear interp.
//   Kernel 1 (merged): per block, compute h1 = silu(feats@W1+b1) for 16
//   entries into LDS, then GEMV vs W2 (lane owns k-pair, h1 read as uniform
//   ds_read_b128 broadcast), silu, dot W3 -> tab. 514 blocks = 2 waves/SIMD.
//   Kernel 2: pairs; tab staged via async global_load_lds (16B/lane, no VGPR
//   round-trip, drained by the vmcnt(0) at __syncthreads); pos staged as
//   float4. Random interp gathers hit LDS (~2-way bank alias = free).
// NOTE (round-2 post-mortem): single-dispatch fusion with device-scope flag
//   spin was 7x SLOWER (72 us) — 131k threads polling agent-scope flags
//   congest the Infinity-Cache coherence point. Two dispatches it is.

#define NPTS   512
#define HDIM   128
#define NBATCH 8
#define TN     8192               // intervals; table has TN+1 entries
#define R0     0.05f
#define RMAX   20.05f
#define DELTA  ((RMAX - R0) / (float)TN)
#define EPB    16                 // entries per block (table build)
#define NBLK_T 514                // 514*16 = 8224 >= TN+1
#define NCHUNK 64
#define CHUNK  2044               // 130816 / 64 exact

#define GLDS16(g, l) __builtin_amdgcn_global_load_lds(                  \
    (const __attribute__((address_space(1))) void*)(g),                 \
    (__attribute__((address_space(3))) void*)(l), 16, 0, 0)

__device__ __forceinline__ float silu_f(float x) {
    float e = __expf(-x);
    return x * __builtin_amdgcn_rcpf(1.0f + e);
}

// ---------------------------------------------------------------------------
// Merged table build: h1 in LDS, then GEMV + silu + W3 contraction.
// Wave w owns entries ebase+4w..4w+3; lane owns k = {2*lane, 2*lane+1}.
// h1 operand is wave-uniform -> ds_read_b128 broadcast (conflict-free).
// Also zeroes d_out (replaces a memset dispatch) and writes entry TN.
// ---------------------------------------------------------------------------
__global__ __launch_bounds__(256) void table_kernel(
    const float* __restrict__ W1, const float* __restrict__ b1,
    const float* __restrict__ W2, const float* __restrict__ b2,
    const float* __restrict__ W3, const float* __restrict__ b3,
    float* __restrict__ tab, float* __restrict__ out)
{
    __shared__ __align__(16) float h1L[EPB][HDIM];   // 8 KB

    const int t     = threadIdx.x;
    const int h     = t & 127;
    const int ebase = blockIdx.x * EPB;

    // Phase A: 16 entries x 128 h = 2048 silu values, 8 per thread.
    const float w1a = W1[h], w1b = W1[HDIM + h], w1c = W1[2 * HDIM + h];
    const float bb1 = b1[h];
    #pragma unroll
    for (int v = 0; v < 8; ++v) {
        const int   eloc = (t >> 7) + 2 * v;          // covers 0..15
        const float r    = R0 + (float)(ebase + eloc) * DELTA;
        const float rinv = __builtin_amdgcn_rcpf(r);
        const float pre  = fmaf(r, w1a,
                           fmaf(rinv, w1b,
                           fmaf(rinv * rinv, w1c, bb1)));
        h1L[eloc][h] = silu_f(pre);
    }
    if (blockIdx.x == 0 && t < NBATCH) out[t] = 0.0f;
    __syncthreads();

    // Phase B: GEMV. W2 row loads are coalesced float2 (512B/wave).
    const int lane = t & 63;
    const int wave = t >> 6;
    const int ew   = wave * 4;

    const float2* __restrict__ W2v = (const float2*)W2;
    const float2 b2v = ((const float2*)b2)[lane];
    float2 acc[4];
    #pragma unroll
    for (int g = 0; g < 4; ++g) acc[g] = b2v;

    #pragma unroll 4
    for (int hh = 0; hh < HDIM; hh += 4) {
        const float2 w2_0 = W2v[(hh + 0) * 64 + lane];
        const float2 w2_1 = W2v[(hh + 1) * 64 + lane];
        const float2 w2_2 = W2v[(hh + 2) * 64 + lane];
        const float2 w2_3 = W2v[(hh + 3) * 64 + lane];
        #pragma unroll
        for (int g = 0; g < 4; ++g) {
            const float4 hv = *(const float4*)&h1L[ew + g][hh];  // broadcast
            acc[g].x = fmaf(hv.x, w2_0.x, acc[g].x);
            acc[g].y = fmaf(hv.x, w2_0.y, acc[g].y);
            acc[g].x = fmaf(hv.y, w2_1.x, acc[g].x);
            acc[g].y = fmaf(hv.y, w2_1.y, acc[g].y);
            acc[g].x = fmaf(hv.z, w2_2.x, acc[g].x);
            acc[g].y = fmaf(hv.z, w2_2.y, acc[g].y);
            acc[g].x = fmaf(hv.w, w2_3.x, acc[g].x);
            acc[g].y = fmaf(hv.w, w2_3.y, acc[g].y);
        }
    }

    const float2 w3v  = ((const float2*)W3)[lane];
    const float bias3 = b3[0];
    #pragma unroll
    for (int g = 0; g < 4; ++g) {
        float s = silu_f(acc[g].x) * w3v.x + silu_f(acc[g].y) * w3v.y;
        #pragma unroll
        for (int o = 32; o; o >>= 1) s += __shfl_xor(s, o, 64);
        const int e = ebase + ew + g;
        if (lane == 0 && e <= TN) tab[e] = s + bias3;
    }
}

// ---------------------------------------------------------------------------
// Pair kernel: unordered-pair enumeration (each pair once, scale = 1.0):
//   t < 130560: d=(t>>9)+1 in [1,255], i=t&511, j=(i+d)&511
//   else:       antipodal (i, i+256), i = t-130560 in [0,256)
// tab staged via async global_load_lds; pos staged as float4 via VGPR
// (needs the float3->float4 reformat; its latency overlaps the async stage).
// ---------------------------------------------------------------------------
__global__ __launch_bounds__(256) void pair_sum_kernel(
    const float* __restrict__ pos, const float* __restrict__ tab,
    float* __restrict__ out)
{
    const int b = blockIdx.x >> 6;         // batch
    const int c = blockIdx.x & (NCHUNK - 1);

    __shared__ __align__(16) float tabL[8448];   // 33 KB (8193 used)
    __shared__ float4 posL[NPTS];                // 8 KB
    __shared__ float  wsum[4];

    const int t  = threadIdx.x;
    const int wv = t >> 6;
    const int ln = t & 63;

    // async direct-to-LDS stage of tab: 33 wave-issues x 1024B.
    // LDS dest is wave-uniform base; HW adds lane*16. Extra issue covers
    // tab[8192] (reads 255 garbage floats past it into LDS, never used).
    #pragma unroll
    for (int k = 0; k < 8; ++k) {
        const int base = (wv * 8 + k) * 256;     // float offset, wave-uniform
        GLDS16(tab + base + ln * 4, &tabL[base]);
    }
    if (wv == 0) GLDS16(tab + 8192 + ln * 4, &tabL[8192]);

    const float* __restrict__ pb = pos + b * (NPTS * 3);
    for (int i = t; i < NPTS; i += 256)
        posL[i] = make_float4(pb[3 * i], pb[3 * i + 1], pb[3 * i + 2], 0.0f);
    __syncthreads();   // compiler drains vmcnt(0) here -> glds data visible

    const float invD = (float)TN / (RMAX - R0);
    float acc = 0.0f;

    const int tend = (c + 1) * CHUNK;
    for (int tt = c * CHUNK + t; tt < tend; tt += 256) {
        int i, j;
        if (tt < 130560) {
            const int d = (tt >> 9) + 1;
            i = tt & 511;
            j = (i + d) & 511;
        } else {
            i = tt - 130560;
            j = i + 256;
        }
        const float4 pi = posL[i];
        const float4 pj = posL[j];
        const float dx = pi.x - pj.x;
        const float dy = pi.y - pj.y;
        const float dz = pi.z - pj.z;
        const float r2 = fmaf(dx, dx, fmaf(dy, dy, dz * dz));
        const float r  = __builtin_amdgcn_sqrtf(r2);
        float x = (r - R0) * invD;
        x = fminf(fmaxf(x, 0.0f), (float)TN - 0.0005f);
        const int   idx = (int)x;
        const float fr  = x - (float)idx;
        const float t0v = tabL[idx];
        const float t1v = tabL[idx + 1];
        acc = fmaf(fr, t1v - t0v, acc + t0v);
    }

    #pragma unroll
    for (int o = 32; o; o >>= 1) acc += __shfl_xor(acc, o, 64);
    if (ln == 0) wsum[wv] = acc;
    __syncthreads();
    if (t == 0)
        atomicAdd(out + b, wsum[0] + wsum[1] + wsum[2] + wsum[3]);
}

extern "C" void kernel_launch(void* const* d_in, const int* in_sizes, int n_in,
                              void* d_out, int out_size, void* d_ws, size_t ws_size,
                              hipStream_t stream) {
    const float* pos = (const float*)d_in[0];
    const float* W1  = (const float*)d_in[1];
    const float* b1  = (const float*)d_in[2];
    const float* W2  = (const float*)d_in[3];
    const float* b2  = (const float*)d_in[4];
    const float* W3  = (const float*)d_in[5];
    const float* b3  = (const float*)d_in[6];
    float*       out = (float*)d_out;

    float* tab = (float*)d_ws;                     // (TN+1) floats (+pad read)

    // Merged h1+GEMV table build: 514 blocks (2 waves/SIMD), also zeroes out[]
    table_kernel<<<dim3(NBLK_T), dim3(256), 0, stream>>>(
        W1, b1, W2, b2, W3, b3, tab, out);

    // Pairs: 8 batches x 64 chunks
    pair_sum_kernel<<<dim3(NBATCH * NCHUNK), dim3(256), 0, stream>>>(pos, tab, out);
}

// Round 4
// 86.830 us; speedup vs baseline: 1.5734x; 1.0188x over previous
//
#include <hip/hip_runtime.h>

// DiscoveryNet: out[b] = 0.5 * sum over ordered off-diagonal pairs of
//   MLP([r, 1/r, 1/r^2]), r = max(dist, 0.05).  v depends only on r and is
//   symmetric => sum over unordered pairs of a 1-D function v(r).
// Plan: tabulate v(r) (TN+1 points); pairs do sqrt + linear interp.
//   Kernel 1: k-split GEMV. Wave w owns k-chunk [32w,32w+32): each block
//   reads W2 exactly ONCE (64 KB) -> aggregate L2 traffic 33 MB (was 131 MB
//   with every wave streaming all of W2). Lane owns a k-pair (float2) and
//   4 of 16 entries; h1 broadcast from LDS (rows padded to 132 floats so the
//   4 per-quad b128 addresses hit disjoint banks). Epilogue: shfl_xor
//   k-reduce + tiny LDS cross-wave combine.
//   Kernel 2: pairs; tab staged via async global_load_lds (16B/lane), pos as
//   float4; random interp gathers hit LDS (~2-way bank alias = free).
// NOTE (round-2 post-mortem): single-dispatch fusion with device-scope flag
//   spin was 7x SLOWER (72 us) — 131k threads polling agent-scope flags
//   congest the Infinity-Cache coherence point. Two dispatches it is.

#define NPTS   512
#define HDIM   128
#define NBATCH 8
#define TN     8192               // intervals; table has TN+1 entries
#define R0     0.05f
#define RMAX   20.05f
#define DELTA  ((RMAX - R0) / (float)TN)
#define EPB    16                 // entries per block (table build)
#define NBLK_T 514                // 514*16 = 8224 >= TN+1
#define NCHUNK 64
#define CHUNK  2044               // 130816 / 64 exact

#define GLDS16(g, l) __builtin_amdgcn_global_load_lds(                  \
    (const __attribute__((address_space(1))) void*)(g),                 \
    (__attribute__((address_space(3))) void*)(l), 16, 0, 0)

__device__ __forceinline__ float silu_f(float x) {
    float e = __expf(-x);
    return x * __builtin_amdgcn_rcpf(1.0f + e);
}

// ---------------------------------------------------------------------------
// Table build, k-split: block computes tab[16b..16b+15].
//   Phase A: h1[16][128] = silu(feats@W1+b1) into LDS (padded rows).
//   Phase B: wave w owns k in [32w,32w+32); lane ln: k-pair k2=ln>>2,
//            entry-group q=ln&3 (entries e=4g+q). acc = b2 + sum_h h1*W2.
//   Epilogue: s = silu(acc).W3 per lane, shfl_xor over k2 (strides 4..32),
//            lanes 0..3 publish per-wave entry partials, one pass combines.
// Also zeroes d_out (replaces a memset dispatch).
// ---------------------------------------------------------------------------
__global__ __launch_bounds__(256) void table_kernel(
    const float* __restrict__ W1, const float* __restrict__ b1,
    const float* __restrict__ W2, const float* __restrict__ b2,
    const float* __restrict__ W3, const float* __restrict__ b3,
    float* __restrict__ tab, float* __restrict__ out)
{
    __shared__ __align__(16) float h1L[EPB][HDIM + 4];   // pad: bank-shift 4/row
    __shared__ float part[4][EPB];

    const int t     = threadIdx.x;
    const int h     = t & 127;
    const int ebase = blockIdx.x * EPB;

    // Phase A: 16 entries x 128 h, 8 per thread.
    const float w1a = W1[h], w1b = W1[HDIM + h], w1c = W1[2 * HDIM + h];
    const float bb1 = b1[h];
    #pragma unroll
    for (int v = 0; v < 8; ++v) {
        const int   eloc = (t >> 7) + 2 * v;          // covers 0..15
        const float r    = R0 + (float)(ebase + eloc) * DELTA;
        const float rinv = __builtin_amdgcn_rcpf(r);
        const float pre  = fmaf(r, w1a,
                           fmaf(rinv, w1b,
                           fmaf(rinv * rinv, w1c, bb1)));
        h1L[eloc][h] = silu_f(pre);
    }
    if (blockIdx.x == 0 && t < NBATCH) out[t] = 0.0f;
    __syncthreads();

    // Phase B: k-split GEMV.
    const int lane = t & 63;
    const int wave = t >> 6;
    const int k2   = lane >> 2;            // k-pair index in chunk, 0..15
    const int q    = lane & 3;             // entry-group: e = 4g+q

    const float2* __restrict__ W2v = (const float2*)W2;   // [h][k-pair]
    const int kp = wave * 16 + k2;                        // global k-pair
    const float2 b2v = ((const float2*)b2)[kp];

    float2 acc[4];
    #pragma unroll
    for (int g = 0; g < 4; ++g) acc[g] = b2v;

    #pragma unroll 4
    for (int hh = 0; hh < HDIM; hh += 4) {
        const float2 w2_0 = W2v[(hh + 0) * 64 + kp];
        const float2 w2_1 = W2v[(hh + 1) * 64 + kp];
        const float2 w2_2 = W2v[(hh + 2) * 64 + kp];
        const float2 w2_3 = W2v[(hh + 3) * 64 + kp];
        #pragma unroll
        for (int g = 0; g < 4; ++g) {
            const float4 hv = *(const float4*)&h1L[4 * g + q][hh];  // broadcast
            acc[g].x = fmaf(hv.x, w2_0.x, acc[g].x);
            acc[g].y = fmaf(hv.x, w2_0.y, acc[g].y);
            acc[g].x = fmaf(hv.y, w2_1.x, acc[g].x);
            acc[g].y = fmaf(hv.y, w2_1.y, acc[g].y);
            acc[g].x = fmaf(hv.z, w2_2.x, acc[g].x);
            acc[g].y = fmaf(hv.z, w2_2.y, acc[g].y);
            acc[g].x = fmaf(hv.w, w2_3.x, acc[g].x);
            acc[g].y = fmaf(hv.w, w2_3.y, acc[g].y);
        }
    }

    // Epilogue: silu + W3 contraction over this lane's 2 k's, then k-reduce.
    const float2 w3v = ((const float2*)W3)[kp];
    float s[4];
    #pragma unroll
    for (int g = 0; g < 4; ++g)
        s[g] = silu_f(acc[g].x) * w3v.x + silu_f(acc[g].y) * w3v.y;
    #pragma unroll
    for (int o = 4; o < 64; o <<= 1) {
        #pragma unroll
        for (int g = 0; g < 4; ++g) s[g] += __shfl_xor(s[g], o, 64);
    }
    if (lane < 4) {
        #pragma unroll
        for (int g = 0; g < 4; ++g) part[wave][4 * g + lane] = s[g];
    }
    __syncthreads();
    if (t < EPB) {
        const int e = ebase + t;
        if (e <= TN)
            tab[e] = part[0][t] + part[1][t] + part[2][t] + part[3][t] + b3[0];
    }
}

// ---------------------------------------------------------------------------
// Pair kernel: unordered-pair enumeration (each pair once, scale = 1.0):
//   t < 130560: d=(t>>9)+1 in [1,255], i=t&511, j=(i+d)&511
//   else:       antipodal (i, i+256), i = t-130560 in [0,256)
// tab staged via async global_load_lds; pos staged as float4 via VGPR
// (needs the float3->float4 reformat; its latency overlaps the async stage).
// ---------------------------------------------------------------------------
__global__ __launch_bounds__(256) void pair_sum_kernel(
    const float* __restrict__ pos, const float* __restrict__ tab,
    float* __restrict__ out)
{
    const int b = blockIdx.x >> 6;         // batch
    const int c = blockIdx.x & (NCHUNK - 1);

    __shared__ __align__(16) float tabL[8448];   // 33 KB (8193 used)
    __shared__ float4 posL[NPTS];                // 8 KB
    __shared__ float  wsum[4];

    const int t  = threadIdx.x;
    const int wv = t >> 6;
    const int ln = t & 63;

    // async direct-to-LDS stage of tab: 33 wave-issues x 1024B.
    // LDS dest is wave-uniform base; HW adds lane*16. Extra issue covers
    // tab[8192] (reads 255 garbage floats past it into LDS, never used).
    #pragma unroll
    for (int k = 0; k < 8; ++k) {
        const int base = (wv * 8 + k) * 256;     // float offset, wave-uniform
        GLDS16(tab + base + ln * 4, &tabL[base]);
    }
    if (wv == 0) GLDS16(tab + 8192 + ln * 4, &tabL[8192]);

    const float* __restrict__ pb = pos + b * (NPTS * 3);
    for (int i = t; i < NPTS; i += 256)
        posL[i] = make_float4(pb[3 * i], pb[3 * i + 1], pb[3 * i + 2], 0.0f);
    __syncthreads();   // compiler drains vmcnt(0) here -> glds data visible

    const float invD = (float)TN / (RMAX - R0);
    float acc = 0.0f;

    const int tend = (c + 1) * CHUNK;
    for (int tt = c * CHUNK + t; tt < tend; tt += 256) {
        int i, j;
        if (tt < 130560) {
            const int d = (tt >> 9) + 1;
            i = tt & 511;
            j = (i + d) & 511;
        } else {
            i = tt - 130560;
            j = i + 256;
        }
        const float4 pi = posL[i];
        const float4 pj = posL[j];
        const float dx = pi.x - pj.x;
        const float dy = pi.y - pj.y;
        const float dz = pi.z - pj.z;
        const float r2 = fmaf(dx, dx, fmaf(dy, dy, dz * dz));
        const float r  = __builtin_amdgcn_sqrtf(r2);
        float x = (r - R0) * invD;
        x = fminf(fmaxf(x, 0.0f), (float)TN - 0.0005f);
        const int   idx = (int)x;
        const float fr  = x - (float)idx;
        const float t0v = tabL[idx];
        const float t1v = tabL[idx + 1];
        acc = fmaf(fr, t1v - t0v, acc + t0v);
    }

    #pragma unroll
    for (int o = 32; o; o >>= 1) acc += __shfl_xor(acc, o, 64);
    if (ln == 0) wsum[wv] = acc;
    __syncthreads();
    if (t == 0)
        atomicAdd(out + b, wsum[0] + wsum[1] + wsum[2] + wsum[3]);
}

extern "C" void kernel_launch(void* const* d_in, const int* in_sizes, int n_in,
                              void* d_out, int out_size, void* d_ws, size_t ws_size,
                              hipStream_t stream) {
    const float* pos = (const float*)d_in[0];
    const float* W1  = (const float*)d_in[1];
    const float* b1  = (const float*)d_in[2];
    const float* W2  = (const float*)d_in[3];
    const float* b2  = (const float*)d_in[4];
    const float* W3  = (const float*)d_in[5];
    const float* b3  = (const float*)d_in[6];
    float*       out = (float*)d_out;

    float* tab = (float*)d_ws;                     // (TN+1) floats (+pad read)

    // k-split table build: 514 blocks, W2 read once per block
    table_kernel<<<dim3(NBLK_T), dim3(256), 0, stream>>>(
        W1, b1, W2, b2, W3, b3, tab, out);

    // Pairs: 8 batches x 64 chunks
    pair_sum_kernel<<<dim3(NBATCH * NCHUNK), dim3(256), 0, stream>>>(pos, tab, out);
}